// Round 4
// baseline (560.229 us; speedup 1.0000x reference)
//
#include <hip/hip_runtime.h>
#include <hip/hip_bf16.h>
#include <cstddef>

#define N_NODES 50000
#define N_EDGES 800000
#define HDIM    128
#define TME     64
#define TMN     64

typedef __attribute__((ext_vector_type(4))) float f32x4;
typedef __attribute__((ext_vector_type(8))) short bf16x8;

// pack offsets (bf16 elements)
#define OFF_EW0T 0
#define OFF_EW0B 16384
#define OFF_EW1  32768
#define OFF_CW0  49152
#define OFF_NW0  65536
#define OFF_NW1  98304
#define PACK_ELEMS 114688

__device__ __forceinline__ float silu(float x) {
    float e = __expf(-x);
    return __fdividef(x, 1.0f + e);
}
__device__ __forceinline__ unsigned short f2bf(float f) {
    union { __hip_bfloat16 h; unsigned short u; } cv;
    cv.h = __float2bfloat16(f);
    return cv.u;
}
__device__ __forceinline__ unsigned int f2bf2(float a, float b) {
    union { __hip_bfloat162 h; unsigned int u; } cv;
    cv.h = __float22bfloat162_rn(float2{a, b});
    return cv.u;
}
__device__ __forceinline__ float bf2f(unsigned short u) {
    return __uint_as_float(((unsigned int)u) << 16);
}

// ---------------- weight pack ----------------
__global__ void pack_weights(const float* __restrict__ eW0, const float* __restrict__ eW1,
                             const float* __restrict__ cW0, const float* __restrict__ nW0,
                             const float* __restrict__ nW1, unsigned short* __restrict__ pack)
{
    int g = blockIdx.x * blockDim.x + threadIdx.x;   // 0 .. 14335
    int f = g >> 6;
    int lane = g & 63;
    const float* W; int base; int rowoff = 0;
    if (f < 32)       { W = eW0; base = OFF_EW0T; }
    else if (f < 64)  { W = eW0; base = OFF_EW0B; f -= 32; rowoff = 128; }
    else if (f < 96)  { W = eW1; base = OFF_EW1;  f -= 64; }
    else if (f < 128) { W = cW0; base = OFF_CW0;  f -= 96; }
    else if (f < 192) { W = nW0; base = OFF_NW0;  f -= 128; }
    else              { W = nW1; base = OFF_NW1;  f -= 192; }
    int KS = (base == OFF_NW0) ? 8 : 4;
    int cb = f / KS, ks = f % KS;
    int col = cb * 16 + (lane & 15);
    int kbase = rowoff + ks * 32 + ((lane >> 4) << 3);
#pragma unroll
    for (int j = 0; j < 8; ++j)
        pack[(size_t)base + ((size_t)(f * 64 + lane) * 8 + j)] =
            f2bf(W[(size_t)(kbase + j) * HDIM + col]);
}

// ---------------- counting sort ----------------
__global__ void hist_kernel(const int* __restrict__ eidx, int* __restrict__ cnt) {
    int e = blockIdx.x * blockDim.x + threadIdx.x;
    if (e < N_EDGES) atomicAdd(&cnt[eidx[e]], 1);
}

__global__ __launch_bounds__(1024)
void scan_kernel(const int* __restrict__ cnt, int* __restrict__ row_start,
                 int* __restrict__ cursor) {
    __shared__ int part[1024];
    const int t = threadIdx.x;
    const int PER = (N_NODES + 1023) / 1024;   // 49
    const int base = t * PER;
    int s = 0;
    for (int i = 0; i < PER; ++i) {
        int idx = base + i;
        if (idx < N_NODES) s += cnt[idx];
    }
    part[t] = s;
    __syncthreads();
    for (int off = 1; off < 1024; off <<= 1) {
        int tmp = (t >= off) ? part[t - off] : 0;
        __syncthreads();
        part[t] += tmp;
        __syncthreads();
    }
    int run = part[t] - s;    // exclusive prefix
    for (int i = 0; i < PER; ++i) {
        int idx = base + i;
        if (idx < N_NODES) {
            row_start[idx] = run;
            cursor[idx]    = run;
            run += cnt[idx];
        }
    }
    if (t == 1023) row_start[N_NODES] = part[1023];
}

__global__ void scatter_kernel(const int* __restrict__ eidx, int* __restrict__ cursor,
                               int* __restrict__ rows_s, int* __restrict__ cols_s) {
    int e = blockIdx.x * blockDim.x + threadIdx.x;
    if (e < N_EDGES) {
        int r = eidx[e];
        int c = eidx[N_EDGES + e];
        int p = atomicAdd(&cursor[r], 1);
        rows_s[p] = r;
        cols_s[p] = c;
    }
}

// ---------------- MFMA layer helper ----------------
template<int KS, int ROWB>
__device__ __forceinline__ void gemm_layer(const unsigned short* __restrict__ Bseg,
                                           const char* __restrict__ Xs,
                                           int lane, int cb, f32x4 acc[4])
{
    const bf16x8* bptr = (const bf16x8*)Bseg + (size_t)(cb * KS) * 64 + lane;
#pragma unroll
    for (int ks = 0; ks < KS; ++ks) {
        bf16x8 b = bptr[(size_t)ks * 64];
#pragma unroll
        for (int rb = 0; rb < 4; ++rb) {
            int row = rb * 16 + (lane & 15);
            int bir = ks * 64 + ((lane >> 4) << 4);
            bf16x8 a = *(const bf16x8*)(Xs + row * ROWB + (bir ^ ((row & 7) << 4)));
            acc[rb] = __builtin_amdgcn_mfma_f32_16x16x32_bf16(a, b, acc[rb], 0, 0, 0);
        }
    }
}

// ---------------- H0 precompute ----------------
__global__ __launch_bounds__(512, 2)
void h0_kernel(const float* __restrict__ h, const float* __restrict__ eb0,
               const unsigned short* __restrict__ pack,
               unsigned short* __restrict__ H0r, unsigned short* __restrict__ H0c)
{
    __shared__ __align__(16) unsigned short Xs[TMN * 128];
    const int tid = threadIdx.x, lane = tid & 63, cb = tid >> 6;
    const int n0 = blockIdx.x * TMN;

    {
        const int nl = tid >> 3, sub = tid & 7, n = n0 + nl;
        if (n < N_NODES) {
            const float4* h4 = (const float4*)(h + (size_t)n * HDIM);
#pragma unroll
            for (int q = 0; q < 4; ++q) {
                float4 f = h4[sub + q * 8];
                uint2 u; u.x = f2bf2(f.x, f.y); u.y = f2bf2(f.z, f.w);
                *(uint2*)((char*)Xs + nl * 256 + (((sub + q * 8) * 8) ^ ((nl & 7) << 4))) = u;
            }
        } else {
            uint2 z{0, 0};
#pragma unroll
            for (int q = 0; q < 4; ++q)
                *(uint2*)((char*)Xs + nl * 256 + (((sub + q * 8) * 8) ^ ((nl & 7) << 4))) = z;
        }
    }
    __syncthreads();

    const int col = cb * 16 + (lane & 15);
    f32x4 acc[4];
    {
        float bias = eb0[col];
#pragma unroll
        for (int rb = 0; rb < 4; ++rb) acc[rb] = f32x4{bias, bias, bias, bias};
        gemm_layer<4, 256>(pack + OFF_EW0T, (const char*)Xs, lane, cb, acc);
#pragma unroll
        for (int rb = 0; rb < 4; ++rb)
#pragma unroll
            for (int r = 0; r < 4; ++r) {
                int row = rb * 16 + ((lane >> 4) << 2) + r, n = n0 + row;
                if (n < N_NODES) H0r[(size_t)n * HDIM + col] = f2bf(acc[rb][r]);
            }
    }
    {
#pragma unroll
        for (int rb = 0; rb < 4; ++rb) acc[rb] = f32x4{0.f, 0.f, 0.f, 0.f};
        gemm_layer<4, 256>(pack + OFF_EW0B, (const char*)Xs, lane, cb, acc);
#pragma unroll
        for (int rb = 0; rb < 4; ++rb)
#pragma unroll
            for (int r = 0; r < 4; ++r) {
                int row = rb * 16 + ((lane >> 4) << 2) + r, n = n0 + row;
                if (n < N_NODES) H0c[(size_t)n * HDIM + col] = f2bf(acc[rb][r]);
            }
    }
}

// ---------------- edge kernel (sorted order) ----------------
__global__ __launch_bounds__(512, 4)
void egnn_edge_kernel(const unsigned short* __restrict__ H0r,
                      const unsigned short* __restrict__ H0c,
                      const float* __restrict__ pos,
                      const int*   __restrict__ rows_s,
                      const int*   __restrict__ cols_s,
                      const float* __restrict__ w256,
                      const float* __restrict__ eb1, const float* __restrict__ cb0,
                      const float* __restrict__ cW1,
                      const unsigned short* __restrict__ pack,
                      float* __restrict__ m_i,
                      float* __restrict__ pos_upd)
{
    __shared__ __align__(16) unsigned short Ya[TME * 128];  // 16KB
    __shared__ __align__(16) unsigned short Yb[TME * 128];  // 16KB
    __shared__ float rad_s[TME];
    __shared__ float dif_s[TME][3];
    __shared__ float cu_s[TME][4];
    __shared__ int   rowb_s[TME];

    const int tid = threadIdx.x, lane = tid & 63, cb = tid >> 6;
    const int e0 = blockIdx.x * TME;

    // ---- phase 0: gather H0r[row]+H0c[col] (sorted rows), radial, SiLU -> Ya ----
    {
        const int el = tid >> 3, sub = tid & 7, idx = e0 + el;
        const int r = rows_s[idx];
        const int c = cols_s[idx];
        float dx = pos[(size_t)r * 3 + 0] - pos[(size_t)c * 3 + 0];
        float dy = pos[(size_t)r * 3 + 1] - pos[(size_t)c * 3 + 1];
        float dz = pos[(size_t)r * 3 + 2] - pos[(size_t)c * 3 + 2];
        float rad = dx * dx + dy * dy + dz * dz;
        if (sub == 0) {
            rad_s[el] = rad;
            dif_s[el][0] = dx; dif_s[el][1] = dy; dif_s[el][2] = dz;
            rowb_s[el] = r;
        }
        const bf16x8* ar = (const bf16x8*)(H0r + (size_t)r * HDIM + sub * 16);
        const bf16x8* ac = (const bf16x8*)(H0c + (size_t)c * HDIM + sub * 16);
        bf16x8 a0 = ar[0], a1 = ar[1];
        bf16x8 c0 = ac[0], c1 = ac[1];
        const float4* wp = (const float4*)(w256 + sub * 16);
        float4 w4[4] = { wp[0], wp[1], wp[2], wp[3] };
        const float* wf = (const float*)w4;
        float v[16];
#pragma unroll
        for (int i = 0; i < 8; ++i) v[i]     = bf2f((unsigned short)a0[i]) + bf2f((unsigned short)c0[i]);
#pragma unroll
        for (int i = 0; i < 8; ++i) v[8 + i] = bf2f((unsigned short)a1[i]) + bf2f((unsigned short)c1[i]);
#pragma unroll
        for (int i = 0; i < 16; ++i) v[i] = silu(fmaf(rad, wf[i], v[i]));
#pragma unroll
        for (int c4 = 0; c4 < 4; ++c4) {
            uint2 u;
            u.x = f2bf2(v[c4 * 4 + 0], v[c4 * 4 + 1]);
            u.y = f2bf2(v[c4 * 4 + 2], v[c4 * 4 + 3]);
            *(uint2*)((char*)Ya + el * 256 + ((sub * 32 + c4 * 8) ^ ((el & 7) << 4))) = u;
        }
    }
    __syncthreads();

    const int col = cb * 16 + (lane & 15);
    f32x4 acc[4];

    // ---- phase 1: m_ij = silu(Ya @ eW1 + eb1) -> Yb (bf16), no atomics ----
    {
        float bias = eb1[col];
#pragma unroll
        for (int rb = 0; rb < 4; ++rb) acc[rb] = f32x4{bias, bias, bias, bias};
        gemm_layer<4, 256>(pack + OFF_EW1, (const char*)Ya, lane, cb, acc);
#pragma unroll
        for (int rb = 0; rb < 4; ++rb)
#pragma unroll
            for (int r = 0; r < 4; ++r) {
                int row = rb * 16 + ((lane >> 4) << 2) + r;
                *(unsigned short*)((char*)Yb + row * 256 + ((col * 2) ^ ((row & 7) << 4))) = f2bf(silu(acc[rb][r]));
            }
    }
    __syncthreads();

    // ---- phase 1.5: segment-reduce Yb columns into m_i (few atomics) ----
    {
        const int rcol = tid & 127;           // column
        const int ch   = tid >> 7;            // chunk of 16 sorted edges
        float run = 0.f;
        int cur = rowb_s[ch * 16];
#pragma unroll
        for (int i = 0; i < 16; ++i) {
            int row = ch * 16 + i;
            int rr = rowb_s[row];
            if (rr != cur) {
                atomicAdd(&m_i[(size_t)cur * HDIM + rcol], run);
                run = 0.f; cur = rr;
            }
            unsigned short u = *(const unsigned short*)((char*)Yb + row * 256 + ((rcol * 2) ^ ((row & 7) << 4)));
            run += bf2f(u);
        }
        atomicAdd(&m_i[(size_t)cur * HDIM + rcol], run);
    }

    // ---- phase 2: coord hidden = silu(Yb @ cW0 + cb0) -> Ya ----
    {
        float bias = cb0[col];
#pragma unroll
        for (int rb = 0; rb < 4; ++rb) acc[rb] = f32x4{bias, bias, bias, bias};
        gemm_layer<4, 256>(pack + OFF_CW0, (const char*)Yb, lane, cb, acc);
#pragma unroll
        for (int rb = 0; rb < 4; ++rb)
#pragma unroll
            for (int r = 0; r < 4; ++r) {
                int row = rb * 16 + ((lane >> 4) << 2) + r;
                *(unsigned short*)((char*)Ya + row * 256 + ((col * 2) ^ ((row & 7) << 4))) = f2bf(silu(acc[rb][r]));
            }
    }
    __syncthreads();

    // ---- phase 3: coord weight dot; per-edge update into LDS ----
    {
        const int el = tid >> 3, sub = tid & 7;
        float p = 0.f;
#pragma unroll
        for (int i = 0; i < 16; ++i) {
            int jj = sub * 16 + i;
            unsigned short u = *(const unsigned short*)((char*)Ya + el * 256 + ((jj * 2) ^ ((el & 7) << 4)));
            p = fmaf(bf2f(u), cW1[jj], p);
        }
        p += __shfl_down(p, 4, 8);
        p += __shfl_down(p, 2, 8);
        p += __shfl_down(p, 1, 8);
        if (sub == 0) {
            float inv = 1.0f / sqrtf(rad_s[el] + 1e-8f);
            float cwv = p * inv;
            cu_s[el][0] = dif_s[el][0] * cwv;
            cu_s[el][1] = dif_s[el][1] * cwv;
            cu_s[el][2] = dif_s[el][2] * cwv;
        }
    }
    __syncthreads();

    // ---- phase 4: segment-reduce pos updates (head threads walk) ----
    if (tid < TME) {
        const int el = tid;
        bool head = (el == 0) || (rowb_s[el] != rowb_s[el - 1]);
        if (head) {
            float sx = 0.f, sy = 0.f, sz = 0.f;
            int r = rowb_s[el];
            int j = el;
            do {
                sx += cu_s[j][0]; sy += cu_s[j][1]; sz += cu_s[j][2];
                ++j;
            } while (j < TME && rowb_s[j] == r);
            atomicAdd(&pos_upd[(size_t)r * 3 + 0], sx);
            atomicAdd(&pos_upd[(size_t)r * 3 + 1], sy);
            atomicAdd(&pos_upd[(size_t)r * 3 + 2], sz);
        }
    }
}

// ---------------- node kernel ----------------
__global__ __launch_bounds__(512, 4)
void egnn_node_kernel(const float* __restrict__ h,
                      const float* __restrict__ pos,
                      const float* __restrict__ m_i,
                      const float* __restrict__ pos_upd,
                      const int*   __restrict__ row_start,
                      const float* __restrict__ nb0, const float* __restrict__ nb1,
                      const unsigned short* __restrict__ pack,
                      float* __restrict__ out_h,
                      float* __restrict__ out_pos)
{
    __shared__ __align__(16) unsigned short Xs[TMN * 256];
    __shared__ __align__(16) unsigned short Ya[TMN * 128];

    const int tid = threadIdx.x, lane = tid & 63, cb = tid >> 6;
    const int n0 = blockIdx.x * TMN;

    if (tid < TMN * 3) {
        int nl = tid / 3, d = tid % 3;
        int n = n0 + nl;
        if (n < N_NODES) {
            float dv = (float)(row_start[n + 1] - row_start[n]);
            out_pos[(size_t)n * 3 + d] =
                pos[(size_t)n * 3 + d] + pos_upd[(size_t)n * 3 + d] / (dv + 1e-6f);
        }
    }

    {
        const int nl = tid >> 3, sub = tid & 7, n = n0 + nl;
        if (n < N_NODES) {
            const float4* h4 = (const float4*)(h   + (size_t)n * HDIM);
            const float4* m4 = (const float4*)(m_i + (size_t)n * HDIM);
#pragma unroll
            for (int q = 0; q < 4; ++q) {
                float4 fh = h4[sub + q * 8];
                float4 fm = m4[sub + q * 8];
                uint2 uh; uh.x = f2bf2(fh.x, fh.y); uh.y = f2bf2(fh.z, fh.w);
                uint2 um; um.x = f2bf2(fm.x, fm.y); um.y = f2bf2(fm.z, fm.w);
                int eh = (sub + q * 8) * 8;
                int em = (128 + (sub + q * 8) * 4) * 2;
                *(uint2*)((char*)Xs + nl * 512 + (eh ^ ((nl & 7) << 4))) = uh;
                *(uint2*)((char*)Xs + nl * 512 + (em ^ ((nl & 7) << 4))) = um;
            }
        } else {
            uint2 z{0, 0};
#pragma unroll
            for (int q = 0; q < 4; ++q) {
                int eh = (sub + q * 8) * 8;
                int em = (128 + (sub + q * 8) * 4) * 2;
                *(uint2*)((char*)Xs + nl * 512 + (eh ^ ((nl & 7) << 4))) = z;
                *(uint2*)((char*)Xs + nl * 512 + (em ^ ((nl & 7) << 4))) = z;
            }
        }
    }
    __syncthreads();

    const int col = cb * 16 + (lane & 15);
    f32x4 acc[4];

    {
        float bias = nb0[col];
#pragma unroll
        for (int rb = 0; rb < 4; ++rb) acc[rb] = f32x4{bias, bias, bias, bias};
        gemm_layer<8, 512>(pack + OFF_NW0, (const char*)Xs, lane, cb, acc);
#pragma unroll
        for (int rb = 0; rb < 4; ++rb)
#pragma unroll
            for (int r = 0; r < 4; ++r) {
                int row = rb * 16 + ((lane >> 4) << 2) + r;
                *(unsigned short*)((char*)Ya + row * 256 + ((col * 2) ^ ((row & 7) << 4))) = f2bf(silu(acc[rb][r]));
            }
    }
    __syncthreads();

    {
        float bias = nb1[col];
#pragma unroll
        for (int rb = 0; rb < 4; ++rb) acc[rb] = f32x4{bias, bias, bias, bias};
        gemm_layer<4, 256>(pack + OFF_NW1, (const char*)Ya, lane, cb, acc);
#pragma unroll
        for (int rb = 0; rb < 4; ++rb)
#pragma unroll
            for (int r = 0; r < 4; ++r) {
                int row = rb * 16 + ((lane >> 4) << 2) + r, n = n0 + row;
                if (n < N_NODES)
                    out_h[(size_t)n * HDIM + col] = h[(size_t)n * HDIM + col] + acc[rb][r];
            }
    }
}

extern "C" void kernel_launch(void* const* d_in, const int* in_sizes, int n_in,
                              void* d_out, int out_size, void* d_ws, size_t ws_size,
                              hipStream_t stream) {
    const float* h    = (const float*)d_in[0];
    const float* pos  = (const float*)d_in[1];
    const int*   eidx = (const int*)  d_in[2];
    const float* eW0  = (const float*)d_in[3];
    const float* eb0  = (const float*)d_in[4];
    const float* eW1  = (const float*)d_in[5];
    const float* eb1  = (const float*)d_in[6];
    const float* nW0  = (const float*)d_in[7];
    const float* nb0  = (const float*)d_in[8];
    const float* nW1  = (const float*)d_in[9];
    const float* nb1  = (const float*)d_in[10];
    const float* cW0  = (const float*)d_in[11];
    const float* cb0  = (const float*)d_in[12];
    const float* cW1  = (const float*)d_in[13];

    float* out_h   = (float*)d_out;
    float* out_pos = out_h + (size_t)N_NODES * HDIM;

    // workspace layout
    float* m_i       = (float*)d_ws;                          // N*128 f32  (zeroed)
    float* pos_upd   = m_i + (size_t)N_NODES * HDIM;          // N*3        (zeroed)
    int*   cnt       = (int*)(pos_upd + (size_t)N_NODES * 3); // N          (zeroed)
    int*   row_start = cnt + N_NODES;                         // N+1
    int*   cursor    = row_start + N_NODES + 1;               // N
    int*   rows_s    = cursor + N_NODES;                      // E
    int*   cols_s    = rows_s + N_EDGES;                      // E
    unsigned short* pack = (unsigned short*)(cols_s + N_EDGES);
    unsigned short* H0r  = pack + PACK_ELEMS;                 // N*128 bf16
    unsigned short* H0c  = H0r + (size_t)N_NODES * HDIM;      // N*128 bf16

    size_t zero_bytes = ((size_t)N_NODES * HDIM + (size_t)N_NODES * 3 + N_NODES) * sizeof(float);
    hipMemsetAsync(m_i, 0, zero_bytes, stream);

    pack_weights<<<56, 256, 0, stream>>>(eW0, eW1, cW0, nW0, nW1, pack);

    hist_kernel<<<(N_EDGES + 255) / 256, 256, 0, stream>>>(eidx, cnt);
    scan_kernel<<<1, 1024, 0, stream>>>(cnt, row_start, cursor);
    scatter_kernel<<<(N_EDGES + 255) / 256, 256, 0, stream>>>(eidx, cursor, rows_s, cols_s);

    h0_kernel<<<(N_NODES + TMN - 1) / TMN, 512, 0, stream>>>(h, eb0, pack, H0r, H0c);

    egnn_edge_kernel<<<N_EDGES / TME, 512, 0, stream>>>(
        H0r, H0c, pos, rows_s, cols_s, eW0 + (size_t)256 * HDIM, eb1, cb0, cW1,
        pack, m_i, pos_upd);

    egnn_node_kernel<<<(N_NODES + TMN - 1) / TMN, 512, 0, stream>>>(
        h, pos, m_i, pos_upd, row_start, nb0, nb1, pack, out_h, out_pos);
}